// Round 8
// baseline (694.618 us; speedup 1.0000x reference)
//
#include <hip/hip_runtime.h>
#include <hip/hip_bf16.h>
#include <stdint.h>

// VectorQuantizer: N=65536 keys[N,64] f32, K=4096 emb[K,64] f32.
// out = concat(samples[N,64], log_probs[N,4096]) f32.
//
// Round-8: instruction diet on vq_main2's hot loop (issue-bound at the
// 4-waves/SIMD VGPR-band cap; more occupancy impossible without spills).
// Carried state replaces recomputed addressing: 8 output pointers (+64B/
// step), 4 threefry counters (+16/step), t_ws pointer; final iteration
// peeled (unconditional prefetch in-loop); gumbel negs folded into
// mul-by-(-ln2) (sign-exact). All numerics bit-identical to round 7.

#define NROWS 65536
#define KCODES 4096
#define NPAIR 32768
#define LP_OFF 4194304ull  // 65536*64

// ws byte offsets
#define WS_T 0u
#define WS_S 65536u
#define WS_LSE 327680u
#define WS_E16 589824u
#define WS_B 1114112u    // 4096*64*3*2B = 1.5 MB
#define WS_PB 2686976u   // 65536 x 3 x float2 = 1.5 MB
#define WS_PS 4259840u   // 65536 x 4 x float  = 1 MB

typedef float f32x4_t __attribute__((ext_vector_type(4)));
typedef short s16x8_t __attribute__((ext_vector_type(8)));

__device__ __forceinline__ uint32_t rotl32(uint32_t x, int r) {
  return (x << r) | (x >> (32 - r));
}

// jax threefry2x32-20, key = (0,1)  (jax.random.key(1)) -- verified r1-r7
__device__ __forceinline__ void threefry(uint32_t x0, uint32_t x1,
                                         uint32_t& o0, uint32_t& o1) {
  const uint32_t k0 = 0u, k1 = 1u, k2 = 0x1BD11BDBu;
  x0 += k0; x1 += k1;
  x0 += x1; x1 = rotl32(x1, 13); x1 ^= x0;
  x0 += x1; x1 = rotl32(x1, 15); x1 ^= x0;
  x0 += x1; x1 = rotl32(x1, 26); x1 ^= x0;
  x0 += x1; x1 = rotl32(x1, 6);  x1 ^= x0;
  x0 += k1; x1 += k2 + 1u;
  x0 += x1; x1 = rotl32(x1, 17); x1 ^= x0;
  x0 += x1; x1 = rotl32(x1, 29); x1 ^= x0;
  x0 += x1; x1 = rotl32(x1, 16); x1 ^= x0;
  x0 += x1; x1 = rotl32(x1, 24); x1 ^= x0;
  x0 += k2; x1 += k0 + 2u;
  x0 += x1; x1 = rotl32(x1, 13); x1 ^= x0;
  x0 += x1; x1 = rotl32(x1, 15); x1 ^= x0;
  x0 += x1; x1 = rotl32(x1, 26); x1 ^= x0;
  x0 += x1; x1 = rotl32(x1, 6);  x1 ^= x0;
  x0 += k0; x1 += k1 + 3u;
  x0 += x1; x1 = rotl32(x1, 17); x1 ^= x0;
  x0 += x1; x1 = rotl32(x1, 29); x1 ^= x0;
  x0 += x1; x1 = rotl32(x1, 16); x1 ^= x0;
  x0 += x1; x1 = rotl32(x1, 24); x1 ^= x0;
  x0 += k1; x1 += k2 + 4u;
  x0 += x1; x1 = rotl32(x1, 13); x1 ^= x0;
  x0 += x1; x1 = rotl32(x1, 15); x1 ^= x0;
  x0 += x1; x1 = rotl32(x1, 26); x1 ^= x0;
  x0 += x1; x1 = rotl32(x1, 6);  x1 ^= x0;
  x0 += k2; x1 += k0 + 5u;
  o0 = x0; o1 = x1;
}

__device__ __forceinline__ float hw_log2(float x) {
  float r;
  asm("v_log_f32 %0, %1" : "=v"(r) : "v"(x));
  return r;
}

// jax gumbel from raw bits: u in [tiny,1), g = -log(-log(u)).
// -(fl(x*c)) == fl(x*(-c)) exactly -> fold both negations into the muls.
__device__ __forceinline__ float gumbel_bits(uint32_t b) {
  float f = __fsub_rn(__uint_as_float(0x3f800000u | (b >> 9)), 1.0f);
  float u = fmaxf(f, 1.17549435e-38f);
  float w = __fmul_rn(hw_log2(u), -0.69314718056f);  // == -ln(u)
  return __fmul_rn(hw_log2(w), -0.69314718056f);     // == -ln(w)
}

__device__ __forceinline__ unsigned short f2bf(float x) {
  uint32_t u = __float_as_uint(x);
  uint32_t r = (u + 0x7fffu + ((u >> 16) & 1u)) >> 16;  // RNE
  return (unsigned short)r;
}
__device__ __forceinline__ float bf2f(unsigned short u) {
  return __uint_as_float((uint32_t)u << 16);
}

// ---- K0: per-code |e|^2 (numpy pairwise-8), e16 row-major, B fragments ----
__global__ void vq_pre(const float* __restrict__ emb, float* __restrict__ t_ws,
                       unsigned short* __restrict__ e16,
                       unsigned short* __restrict__ wsb) {
  int code = blockIdx.x * 256 + threadIdx.x;
  if (code >= KCODES) return;
  const float* e = emb + (size_t)code * 64;
  float v[64];
#pragma unroll
  for (int i = 0; i < 64; ++i) v[i] = e[i];
  float r[8];
#pragma unroll
  for (int j = 0; j < 8; ++j) r[j] = __fmul_rn(v[j], v[j]);
#pragma unroll
  for (int m = 1; m < 8; ++m)
#pragma unroll
    for (int j = 0; j < 8; ++j) r[j] = __fadd_rn(r[j], __fmul_rn(v[m * 8 + j], v[m * 8 + j]));
  t_ws[code] = __fadd_rn(__fadd_rn(__fadd_rn(r[0], r[1]), __fadd_rn(r[2], r[3])),
                         __fadd_rn(__fadd_rn(r[4], r[5]), __fadd_rn(r[6], r[7])));
  const int ct = code >> 4, col = code & 15;
#pragma unroll
  for (int h = 0; h < 2; ++h) {
#pragma unroll
    for (int kg = 0; kg < 4; ++kg) {
      s16x8_t c0, c1, c2;
#pragma unroll
      for (int j = 0; j < 8; ++j) {
        float x = v[h * 32 + kg * 8 + j];
        unsigned short b0 = f2bf(x);
        float r1 = __fsub_rn(x, bf2f(b0));
        unsigned short b1 = f2bf(r1);
        float r2 = __fsub_rn(r1, bf2f(b1));
        unsigned short b2 = f2bf(r2);
        c0[j] = (short)b0; c1[j] = (short)b1; c2[j] = (short)b2;
      }
      *(s16x8_t*)(e16 + (size_t)code * 64 + h * 32 + kg * 8) = c0;
      size_t base = ((size_t)(ct * 6 + h) * 64 + kg * 16 + col) * 8;
      *(s16x8_t*)(wsb + base) = c0;                       // s=0
      *(s16x8_t*)(wsb + base + (size_t)2 * 64 * 8) = c1;  // s=1
      *(s16x8_t*)(wsb + base + (size_t)4 * 64 * 8) = c2;  // s=2
    }
  }
}

// ---- K0b: per-row |k|^2 exact pairwise-8 ----
__global__ void vq_prek(const float* __restrict__ keys, float* __restrict__ s_ws) {
  int row = blockIdx.x * 256 + threadIdx.x;
  const float* p = keys + (size_t)row * 64;
  float v[64];
#pragma unroll
  for (int i = 0; i < 64; ++i) v[i] = p[i];
  float r[8];
#pragma unroll
  for (int j = 0; j < 8; ++j) r[j] = __fmul_rn(v[j], v[j]);
#pragma unroll
  for (int m = 1; m < 8; ++m)
#pragma unroll
    for (int j = 0; j < 8; ++j) r[j] = __fadd_rn(r[j], __fmul_rn(v[m * 8 + j], v[m * 8 + j]));
  s_ws[row] = __fadd_rn(__fadd_rn(__fadd_rn(r[0], r[1]), __fadd_rn(r[2], r[3])),
                        __fadd_rn(__fadd_rn(r[4], r[5]), __fadd_rn(r[6], r[7])));
}

// ---- K1a: partial sumexp via bf16 MFMA, 32 rows/wave, ct-quarter split ----
__global__ __launch_bounds__(256, 6) void vq_lsep(
    const float* __restrict__ keys, const unsigned short* __restrict__ e16,
    const float* __restrict__ t_ws, float* __restrict__ pS) {
  const int tid = threadIdx.x;
  const int lane = tid & 63;
  const int wv = blockIdx.x * 4 + (tid >> 6);
  const int grp = wv >> 2;
  const int qt = wv & 3;
  const int mrow = lane & 15, kg = lane >> 4;
  const int nlo = grp * 16, nhi = nlo + NPAIR;

  s16x8_t aL0, aL1, aH0, aH1;
  {
    const float* pL = keys + (size_t)(nlo + mrow) * 64 + kg * 8;
    const float* pH = keys + (size_t)(nhi + mrow) * 64 + kg * 8;
#pragma unroll
    for (int j = 0; j < 8; ++j) {
      aL0[j] = (short)f2bf(pL[j]);
      aL1[j] = (short)f2bf(pL[32 + j]);
      aH0[j] = (short)f2bf(pH[j]);
      aH1[j] = (short)f2bf(pH[32 + j]);
    }
  }

  float SL0 = 0.f, SL1 = 0.f, SL2 = 0.f, SL3 = 0.f;
  float SH0 = 0.f, SH1 = 0.f, SH2 = 0.f, SH3 = 0.f;

  for (int ct = qt * 64; ct < qt * 64 + 64; ++ct) {
    const int col = ct * 16 + mrow;
    const s16x8_t b0 = *(const s16x8_t*)(e16 + (size_t)col * 64 + kg * 8);
    const s16x8_t b1 = *(const s16x8_t*)(e16 + (size_t)col * 64 + 32 + kg * 8);
    f32x4_t accL = {0.f, 0.f, 0.f, 0.f}, accH = {0.f, 0.f, 0.f, 0.f};
    accL = __builtin_amdgcn_mfma_f32_16x16x32_bf16(aL0, b0, accL, 0, 0, 0);
    accH = __builtin_amdgcn_mfma_f32_16x16x32_bf16(aH0, b0, accH, 0, 0, 0);
    accL = __builtin_amdgcn_mfma_f32_16x16x32_bf16(aL1, b1, accL, 0, 0, 0);
    accH = __builtin_amdgcn_mfma_f32_16x16x32_bf16(aH1, b1, accH, 0, 0, 0);
    const float tc = t_ws[col];
    SL0 += __expf(2.f * accL[0] - tc);
    SL1 += __expf(2.f * accL[1] - tc);
    SL2 += __expf(2.f * accL[2] - tc);
    SL3 += __expf(2.f * accL[3] - tc);
    SH0 += __expf(2.f * accH[0] - tc);
    SH1 += __expf(2.f * accH[1] - tc);
    SH2 += __expf(2.f * accH[2] - tc);
    SH3 += __expf(2.f * accH[3] - tc);
  }
#pragma unroll
  for (int m = 1; m <= 8; m <<= 1) {
    SL0 += __shfl_xor(SL0, m); SL1 += __shfl_xor(SL1, m);
    SL2 += __shfl_xor(SL2, m); SL3 += __shfl_xor(SL3, m);
    SH0 += __shfl_xor(SH0, m); SH1 += __shfl_xor(SH1, m);
    SH2 += __shfl_xor(SH2, m); SH3 += __shfl_xor(SH3, m);
  }
  if (mrow == 0) {
    pS[(size_t)(nlo + kg * 4 + 0) * 4 + qt] = SL0;
    pS[(size_t)(nlo + kg * 4 + 1) * 4 + qt] = SL1;
    pS[(size_t)(nlo + kg * 4 + 2) * 4 + qt] = SL2;
    pS[(size_t)(nlo + kg * 4 + 3) * 4 + qt] = SL3;
    pS[(size_t)(nhi + kg * 4 + 0) * 4 + qt] = SH0;
    pS[(size_t)(nhi + kg * 4 + 1) * 4 + qt] = SH1;
    pS[(size_t)(nhi + kg * 4 + 2) * 4 + qt] = SH2;
    pS[(size_t)(nhi + kg * 4 + 3) * 4 + qt] = SH3;
  }
}

// ---- K1b: lse[row] = log(sum of quarters) - |k_row|^2 ----
__global__ __launch_bounds__(256) void vq_lsefin(const float* __restrict__ pS,
                                                 const float* __restrict__ s_ws,
                                                 float* __restrict__ lse_ws) {
  const int row = blockIdx.x * 256 + threadIdx.x;
  const float4 q = *(const float4*)(pS + (size_t)row * 4);
  const float S = (q.x + q.y) + (q.z + q.w);
  lse_ws[row] = logf(S) - s_ws[row];
}

// ---- K2: split-bf16 MFMA logits + gumbel partial-argmax + log_probs ----
#define TERM(sa, sb)                                                             \
  accL = __builtin_amdgcn_mfma_f32_16x16x32_bf16(aL[sa][0], B[(sb)*2+0], accL, 0, 0, 0); \
  accH = __builtin_amdgcn_mfma_f32_16x16x32_bf16(aH[sa][0], B[(sb)*2+0], accH, 0, 0, 0); \
  accL = __builtin_amdgcn_mfma_f32_16x16x32_bf16(aL[sa][1], B[(sb)*2+1], accL, 0, 0, 0); \
  accH = __builtin_amdgcn_mfma_f32_16x16x32_bf16(aH[sa][1], B[(sb)*2+1], accH, 0, 0, 0);

// per-step epilogue: all carried state, no recomputed addressing
#define STEP_BODY()                                                              \
  {                                                                              \
    const float tk = *tp;                                                        \
    tp += 16;                                                                    \
    const int k = (int)(jv[0] & 4095u);                                          \
    _Pragma("unroll")                                                            \
    for (int r = 0; r < 4; ++r) {                                                \
      uint32_t o0, o1;                                                           \
      threefry(jv[r], jv[r] + 0x08000000u, o0, o1);                              \
      jv[r] += 16u;                                                              \
      const float lL = __fsub_rn(__fsub_rn(__fmul_rn(2.0f, accL[r]), sL[r]), tk);\
      const float lH = __fsub_rn(__fsub_rn(__fmul_rn(2.0f, accH[r]), sH[r]), tk);\
      const float vL = __fadd_rn(lL, gumbel_bits(o0));                           \
      const float vH = __fadd_rn(lH, gumbel_bits(o1));                           \
      if (vL > bestL[r]) { bestL[r] = vL; biL[r] = k; }                          \
      if (vH > bestH[r]) { bestH[r] = vH; biH[r] = k; }                          \
      *pL[r] = __fsub_rn(lL, lseL[r]);                                           \
      pL[r] += 16;                                                               \
      *pH[r] = __fsub_rn(lH, lseH[r]);                                           \
      pH[r] += 16;                                                               \
    }                                                                            \
  }

__global__ __launch_bounds__(256, 3) void vq_main2(
    const float* __restrict__ keys, const float* __restrict__ emb,
    const float* __restrict__ t_ws, const float* __restrict__ s_ws,
    const float* __restrict__ lse_ws, const unsigned short* __restrict__ wsb,
    float2* __restrict__ pb_ws, float* __restrict__ out) {
  const int tid = threadIdx.x;
  const int lane = tid & 63;
  const int wv = blockIdx.x * 4 + (tid >> 6);
  const int grp = wv / 3;
  const int seg = wv - grp * 3;
  const int ct0 = (seg == 0) ? 0 : (seg == 1 ? 86 : 171);
  const int ctN = (seg == 0) ? 86 : (seg == 1 ? 171 : 256);
  const int r16 = lane & 15;
  const int kg = lane >> 4;
  const int nlo = grp * 16, nhi = nlo + NPAIR;

  s16x8_t aL[3][2], aH[3][2];
  {
    const float* pLk = keys + (size_t)(nlo + r16) * 64 + kg * 8;
    const float* pHk = keys + (size_t)(nhi + r16) * 64 + kg * 8;
#pragma unroll
    for (int h = 0; h < 2; ++h) {
#pragma unroll
      for (int j = 0; j < 8; ++j) {
        float x = pLk[h * 32 + j];
        unsigned short b0 = f2bf(x);
        float r1 = __fsub_rn(x, bf2f(b0));
        unsigned short b1 = f2bf(r1);
        float r2 = __fsub_rn(r1, bf2f(b1));
        aL[0][h][j] = (short)b0; aL[1][h][j] = (short)b1; aL[2][h][j] = (short)f2bf(r2);
        x = pHk[h * 32 + j];
        b0 = f2bf(x); r1 = __fsub_rn(x, bf2f(b0)); b1 = f2bf(r1);
        r2 = __fsub_rn(r1, bf2f(b1));
        aH[0][h][j] = (short)b0; aH[1][h][j] = (short)b1; aH[2][h][j] = (short)f2bf(r2);
      }
    }
  }

  float sL[4], sH[4], lseL[4], lseH[4];
#pragma unroll
  for (int r = 0; r < 4; ++r) {
    sL[r] = s_ws[nlo + kg * 4 + r];
    sH[r] = s_ws[nhi + kg * 4 + r];
    lseL[r] = lse_ws[nlo + kg * 4 + r];
    lseH[r] = lse_ws[nhi + kg * 4 + r];
  }

  // carried state: threefry counters, output pointers, t pointer
  float* outLP = out + LP_OFF;
  uint32_t jv[4];
  float* pL[4];
  float* pH[4];
#pragma unroll
  for (int r = 0; r < 4; ++r) {
    jv[r] = (uint32_t)(nlo + kg * 4 + r) * 4096u + (uint32_t)r16 + (uint32_t)(ct0 * 16);
    pL[r] = outLP + (size_t)(nlo + kg * 4 + r) * 4096u + (size_t)(r16 + ct0 * 16);
    pH[r] = outLP + (size_t)(nhi + kg * 4 + r) * 4096u + (size_t)(r16 + ct0 * 16);
  }
  const float* tp = t_ws + ct0 * 16 + r16;

  float bestL[4], bestH[4];
  int biL[4], biH[4];
#pragma unroll
  for (int r = 0; r < 4; ++r) {
    bestL[r] = bestH[r] = -__builtin_inff();
    biL[r] = biH[r] = 0;
  }

  const s16x8_t* bp = (const s16x8_t*)wsb + (size_t)ct0 * 6 * 64 + lane;
  s16x8_t B[6];
#pragma unroll
  for (int f = 0; f < 6; ++f) B[f] = bp[f * 64];

  // main loop (unconditional prefetch), final iteration peeled
  for (int ct = ct0; ct < ctN - 1; ++ct) {
    f32x4_t accL = {0.f, 0.f, 0.f, 0.f}, accH = {0.f, 0.f, 0.f, 0.f};
    TERM(1, 1) TERM(2, 0) TERM(0, 2) TERM(1, 0) TERM(0, 1) TERM(0, 0)
    bp += 6 * 64;
#pragma unroll
    for (int f = 0; f < 6; ++f) B[f] = bp[f * 64];
    STEP_BODY()
  }
  {
    f32x4_t accL = {0.f, 0.f, 0.f, 0.f}, accH = {0.f, 0.f, 0.f, 0.f};
    TERM(1, 1) TERM(2, 0) TERM(0, 2) TERM(1, 0) TERM(0, 1) TERM(0, 0)
    STEP_BODY()
  }

  // reduce across the 16 lanes of each kg group (first-index tiebreak)
#pragma unroll
  for (int r = 0; r < 4; ++r) {
#pragma unroll
    for (int m = 1; m <= 8; m <<= 1) {
      float ov = __shfl_xor(bestL[r], m);
      int oi = __shfl_xor(biL[r], m);
      if (ov > bestL[r] || (ov == bestL[r] && oi < biL[r])) { bestL[r] = ov; biL[r] = oi; }
      ov = __shfl_xor(bestH[r], m);
      oi = __shfl_xor(biH[r], m);
      if (ov > bestH[r] || (ov == bestH[r] && oi < biH[r])) { bestH[r] = ov; biH[r] = oi; }
    }
  }

  // partial (best, idx) per row per ct-segment
  if (r16 == 0) {
#pragma unroll
    for (int r = 0; r < 4; ++r) {
      pb_ws[(size_t)(nlo + kg * 4 + r) * 3 + seg] =
          make_float2(bestL[r], __int_as_float(biL[r]));
      pb_ws[(size_t)(nhi + kg * 4 + r) * 3 + seg] =
          make_float2(bestH[r], __int_as_float(biH[r]));
    }
  }
}

// ---- K3: merge 3 ct-segments, gather winning code, write samples ----
__global__ __launch_bounds__(256) void vq_fin(const float* __restrict__ keys,
                                              const float* __restrict__ emb,
                                              const float2* __restrict__ pb_ws,
                                              float* __restrict__ out) {
  const int t = blockIdx.x * 256 + threadIdx.x;
  const int row = t >> 4, l16 = t & 15;
  const float2 a = pb_ws[(size_t)row * 3 + 0];
  const float2 b = pb_ws[(size_t)row * 3 + 1];
  const float2 c = pb_ws[(size_t)row * 3 + 2];
  float bv = a.x;
  int bi = __float_as_int(a.y);
  if (b.x > bv) { bv = b.x; bi = __float_as_int(b.y); }
  if (c.x > bv) { bv = c.x; bi = __float_as_int(c.y); }
  const float4 qq = *(const float4*)(emb + (size_t)bi * 64 + l16 * 4);
  const float4 kv = *(const float4*)(keys + (size_t)row * 64 + l16 * 4);
  float4 rr;
  rr.x = __fadd_rn(kv.x, __fsub_rn(qq.x, kv.x));
  rr.y = __fadd_rn(kv.y, __fsub_rn(qq.y, kv.y));
  rr.z = __fadd_rn(kv.z, __fsub_rn(qq.z, kv.z));
  rr.w = __fadd_rn(kv.w, __fsub_rn(qq.w, kv.w));
  *(float4*)(out + (size_t)row * 64 + l16 * 4) = rr;
}

extern "C" void kernel_launch(void* const* d_in, const int* in_sizes, int n_in,
                              void* d_out, int out_size, void* d_ws, size_t ws_size,
                              hipStream_t stream) {
  const float* keys = (const float*)d_in[0];
  const float* emb = (const float*)d_in[1];
  float* out = (float*)d_out;
  char* w = (char*)d_ws;
  float* t_ws = (float*)(w + WS_T);
  float* s_ws = (float*)(w + WS_S);
  float* lse_ws = (float*)(w + WS_LSE);
  unsigned short* e16 = (unsigned short*)(w + WS_E16);
  unsigned short* wsb = (unsigned short*)(w + WS_B);
  float2* pb_ws = (float2*)(w + WS_PB);
  float* pS_ws = (float*)(w + WS_PS);

  vq_pre<<<16, 256, 0, stream>>>(emb, t_ws, e16, wsb);
  vq_prek<<<256, 256, 0, stream>>>(keys, s_ws);
  vq_lsep<<<2048, 256, 0, stream>>>(keys, e16, t_ws, pS_ws);
  vq_lsefin<<<256, 256, 0, stream>>>(pS_ws, s_ws, lse_ws);
  vq_main2<<<1536, 256, 0, stream>>>(keys, emb, t_ws, s_ws, lse_ws, wsb, pb_ws, out);
  vq_fin<<<4096, 256, 0, stream>>>(keys, emb, pb_ws, out);
}

// Round 9
// 646.590 us; speedup vs baseline: 1.0743x; 1.0743x over previous
//
#include <hip/hip_runtime.h>
#include <hip/hip_bf16.h>
#include <stdint.h>

// VectorQuantizer: N=65536 keys[N,64] f32, K=4096 emb[K,64] f32.
// out = concat(samples[N,64], log_probs[N,4096]) f32.
//
// Round-9: revert vq_main2 to the round-7 structure (round-8's carried-
// pointer diet regressed 665->695: compiler already folded addressing;
// +16 VGPR live state hurt). One addition: log_probs stores are
// NON-TEMPORAL (nt) -- 1.07 GB of write-once data no longer flushes the
// 4MB/XCD L2 that keeps the B-fragment table hot. Values bit-identical.

#define NROWS 65536
#define KCODES 4096
#define NPAIR 32768
#define LP_OFF 4194304ull  // 65536*64

// ws byte offsets
#define WS_T 0u
#define WS_S 65536u
#define WS_LSE 327680u
#define WS_E16 589824u
#define WS_B 1114112u    // 4096*64*3*2B = 1.5 MB
#define WS_PB 2686976u   // 65536 x 3 x float2 = 1.5 MB
#define WS_PS 4259840u   // 65536 x 4 x float  = 1 MB

typedef float f32x4_t __attribute__((ext_vector_type(4)));
typedef short s16x8_t __attribute__((ext_vector_type(8)));

__device__ __forceinline__ uint32_t rotl32(uint32_t x, int r) {
  return (x << r) | (x >> (32 - r));
}

// jax threefry2x32-20, key = (0,1)  (jax.random.key(1)) -- verified r1-r8
__device__ __forceinline__ void threefry(uint32_t x0, uint32_t x1,
                                         uint32_t& o0, uint32_t& o1) {
  const uint32_t k0 = 0u, k1 = 1u, k2 = 0x1BD11BDBu;
  x0 += k0; x1 += k1;
  x0 += x1; x1 = rotl32(x1, 13); x1 ^= x0;
  x0 += x1; x1 = rotl32(x1, 15); x1 ^= x0;
  x0 += x1; x1 = rotl32(x1, 26); x1 ^= x0;
  x0 += x1; x1 = rotl32(x1, 6);  x1 ^= x0;
  x0 += k1; x1 += k2 + 1u;
  x0 += x1; x1 = rotl32(x1, 17); x1 ^= x0;
  x0 += x1; x1 = rotl32(x1, 29); x1 ^= x0;
  x0 += x1; x1 = rotl32(x1, 16); x1 ^= x0;
  x0 += x1; x1 = rotl32(x1, 24); x1 ^= x0;
  x0 += k2; x1 += k0 + 2u;
  x0 += x1; x1 = rotl32(x1, 13); x1 ^= x0;
  x0 += x1; x1 = rotl32(x1, 15); x1 ^= x0;
  x0 += x1; x1 = rotl32(x1, 26); x1 ^= x0;
  x0 += x1; x1 = rotl32(x1, 6);  x1 ^= x0;
  x0 += k0; x1 += k1 + 3u;
  x0 += x1; x1 = rotl32(x1, 17); x1 ^= x0;
  x0 += x1; x1 = rotl32(x1, 29); x1 ^= x0;
  x0 += x1; x1 = rotl32(x1, 16); x1 ^= x0;
  x0 += x1; x1 = rotl32(x1, 24); x1 ^= x0;
  x0 += k1; x1 += k2 + 4u;
  x0 += x1; x1 = rotl32(x1, 13); x1 ^= x0;
  x0 += x1; x1 = rotl32(x1, 15); x1 ^= x0;
  x0 += x1; x1 = rotl32(x1, 26); x1 ^= x0;
  x0 += x1; x1 = rotl32(x1, 6);  x1 ^= x0;
  x0 += k2; x1 += k0 + 5u;
  o0 = x0; o1 = x1;
}

// ln(x) = v_log_f32(x) * ln2 ; inputs here always normal, never NaN/Inf.
__device__ __forceinline__ float hw_log(float x) {
  float r;
  asm("v_log_f32 %0, %1" : "=v"(r) : "v"(x));
  return __fmul_rn(r, 0.69314718056f);
}

// jax gumbel from raw bits: u in [tiny,1), g = -log(-log(u))
__device__ __forceinline__ float gumbel_bits(uint32_t b) {
  float f = __fsub_rn(__uint_as_float(0x3f800000u | (b >> 9)), 1.0f);
  float u = fmaxf(f, 1.17549435e-38f);
  float w = -hw_log(u);   // w in [5.96e-8, 87.4], normal
  return -hw_log(w);
}

__device__ __forceinline__ unsigned short f2bf(float x) {
  uint32_t u = __float_as_uint(x);
  uint32_t r = (u + 0x7fffu + ((u >> 16) & 1u)) >> 16;  // RNE
  return (unsigned short)r;
}
__device__ __forceinline__ float bf2f(unsigned short u) {
  return __uint_as_float((uint32_t)u << 16);
}

// ---- K0: per-code |e|^2 (numpy pairwise-8), e16 row-major, B fragments ----
__global__ void vq_pre(const float* __restrict__ emb, float* __restrict__ t_ws,
                       unsigned short* __restrict__ e16,
                       unsigned short* __restrict__ wsb) {
  int code = blockIdx.x * 256 + threadIdx.x;
  if (code >= KCODES) return;
  const float* e = emb + (size_t)code * 64;
  float v[64];
#pragma unroll
  for (int i = 0; i < 64; ++i) v[i] = e[i];
  float r[8];
#pragma unroll
  for (int j = 0; j < 8; ++j) r[j] = __fmul_rn(v[j], v[j]);
#pragma unroll
  for (int m = 1; m < 8; ++m)
#pragma unroll
    for (int j = 0; j < 8; ++j) r[j] = __fadd_rn(r[j], __fmul_rn(v[m * 8 + j], v[m * 8 + j]));
  t_ws[code] = __fadd_rn(__fadd_rn(__fadd_rn(r[0], r[1]), __fadd_rn(r[2], r[3])),
                         __fadd_rn(__fadd_rn(r[4], r[5]), __fadd_rn(r[6], r[7])));
  const int ct = code >> 4, col = code & 15;
#pragma unroll
  for (int h = 0; h < 2; ++h) {
#pragma unroll
    for (int kg = 0; kg < 4; ++kg) {
      s16x8_t c0, c1, c2;
#pragma unroll
      for (int j = 0; j < 8; ++j) {
        float x = v[h * 32 + kg * 8 + j];
        unsigned short b0 = f2bf(x);
        float r1 = __fsub_rn(x, bf2f(b0));
        unsigned short b1 = f2bf(r1);
        float r2 = __fsub_rn(r1, bf2f(b1));
        unsigned short b2 = f2bf(r2);
        c0[j] = (short)b0; c1[j] = (short)b1; c2[j] = (short)b2;
      }
      *(s16x8_t*)(e16 + (size_t)code * 64 + h * 32 + kg * 8) = c0;
      size_t base = ((size_t)(ct * 6 + h) * 64 + kg * 16 + col) * 8;
      *(s16x8_t*)(wsb + base) = c0;                       // s=0
      *(s16x8_t*)(wsb + base + (size_t)2 * 64 * 8) = c1;  // s=1
      *(s16x8_t*)(wsb + base + (size_t)4 * 64 * 8) = c2;  // s=2
    }
  }
}

// ---- K0b: per-row |k|^2 exact pairwise-8 ----
__global__ void vq_prek(const float* __restrict__ keys, float* __restrict__ s_ws) {
  int row = blockIdx.x * 256 + threadIdx.x;
  const float* p = keys + (size_t)row * 64;
  float v[64];
#pragma unroll
  for (int i = 0; i < 64; ++i) v[i] = p[i];
  float r[8];
#pragma unroll
  for (int j = 0; j < 8; ++j) r[j] = __fmul_rn(v[j], v[j]);
#pragma unroll
  for (int m = 1; m < 8; ++m)
#pragma unroll
    for (int j = 0; j < 8; ++j) r[j] = __fadd_rn(r[j], __fmul_rn(v[m * 8 + j], v[m * 8 + j]));
  s_ws[row] = __fadd_rn(__fadd_rn(__fadd_rn(r[0], r[1]), __fadd_rn(r[2], r[3])),
                        __fadd_rn(__fadd_rn(r[4], r[5]), __fadd_rn(r[6], r[7])));
}

// ---- K1a: partial sumexp via bf16 MFMA, 32 rows/wave, ct-quarter split ----
__global__ __launch_bounds__(256, 6) void vq_lsep(
    const float* __restrict__ keys, const unsigned short* __restrict__ e16,
    const float* __restrict__ t_ws, float* __restrict__ pS) {
  const int tid = threadIdx.x;
  const int lane = tid & 63;
  const int wv = blockIdx.x * 4 + (tid >> 6);
  const int grp = wv >> 2;
  const int qt = wv & 3;
  const int mrow = lane & 15, kg = lane >> 4;
  const int nlo = grp * 16, nhi = nlo + NPAIR;

  s16x8_t aL0, aL1, aH0, aH1;
  {
    const float* pL = keys + (size_t)(nlo + mrow) * 64 + kg * 8;
    const float* pH = keys + (size_t)(nhi + mrow) * 64 + kg * 8;
#pragma unroll
    for (int j = 0; j < 8; ++j) {
      aL0[j] = (short)f2bf(pL[j]);
      aL1[j] = (short)f2bf(pL[32 + j]);
      aH0[j] = (short)f2bf(pH[j]);
      aH1[j] = (short)f2bf(pH[32 + j]);
    }
  }

  float SL0 = 0.f, SL1 = 0.f, SL2 = 0.f, SL3 = 0.f;
  float SH0 = 0.f, SH1 = 0.f, SH2 = 0.f, SH3 = 0.f;

  for (int ct = qt * 64; ct < qt * 64 + 64; ++ct) {
    const int col = ct * 16 + mrow;
    const s16x8_t b0 = *(const s16x8_t*)(e16 + (size_t)col * 64 + kg * 8);
    const s16x8_t b1 = *(const s16x8_t*)(e16 + (size_t)col * 64 + 32 + kg * 8);
    f32x4_t accL = {0.f, 0.f, 0.f, 0.f}, accH = {0.f, 0.f, 0.f, 0.f};
    accL = __builtin_amdgcn_mfma_f32_16x16x32_bf16(aL0, b0, accL, 0, 0, 0);
    accH = __builtin_amdgcn_mfma_f32_16x16x32_bf16(aH0, b0, accH, 0, 0, 0);
    accL = __builtin_amdgcn_mfma_f32_16x16x32_bf16(aL1, b1, accL, 0, 0, 0);
    accH = __builtin_amdgcn_mfma_f32_16x16x32_bf16(aH1, b1, accH, 0, 0, 0);
    const float tc = t_ws[col];
    SL0 += __expf(2.f * accL[0] - tc);
    SL1 += __expf(2.f * accL[1] - tc);
    SL2 += __expf(2.f * accL[2] - tc);
    SL3 += __expf(2.f * accL[3] - tc);
    SH0 += __expf(2.f * accH[0] - tc);
    SH1 += __expf(2.f * accH[1] - tc);
    SH2 += __expf(2.f * accH[2] - tc);
    SH3 += __expf(2.f * accH[3] - tc);
  }
#pragma unroll
  for (int m = 1; m <= 8; m <<= 1) {
    SL0 += __shfl_xor(SL0, m); SL1 += __shfl_xor(SL1, m);
    SL2 += __shfl_xor(SL2, m); SL3 += __shfl_xor(SL3, m);
    SH0 += __shfl_xor(SH0, m); SH1 += __shfl_xor(SH1, m);
    SH2 += __shfl_xor(SH2, m); SH3 += __shfl_xor(SH3, m);
  }
  if (mrow == 0) {
    pS[(size_t)(nlo + kg * 4 + 0) * 4 + qt] = SL0;
    pS[(size_t)(nlo + kg * 4 + 1) * 4 + qt] = SL1;
    pS[(size_t)(nlo + kg * 4 + 2) * 4 + qt] = SL2;
    pS[(size_t)(nlo + kg * 4 + 3) * 4 + qt] = SL3;
    pS[(size_t)(nhi + kg * 4 + 0) * 4 + qt] = SH0;
    pS[(size_t)(nhi + kg * 4 + 1) * 4 + qt] = SH1;
    pS[(size_t)(nhi + kg * 4 + 2) * 4 + qt] = SH2;
    pS[(size_t)(nhi + kg * 4 + 3) * 4 + qt] = SH3;
  }
}

// ---- K1b: lse[row] = log(sum of quarters) - |k_row|^2 ----
__global__ __launch_bounds__(256) void vq_lsefin(const float* __restrict__ pS,
                                                 const float* __restrict__ s_ws,
                                                 float* __restrict__ lse_ws) {
  const int row = blockIdx.x * 256 + threadIdx.x;
  const float4 q = *(const float4*)(pS + (size_t)row * 4);
  const float S = (q.x + q.y) + (q.z + q.w);
  lse_ws[row] = logf(S) - s_ws[row];
}

// ---- K2: split-bf16 MFMA logits + gumbel partial-argmax + log_probs ----
// wave wv: grp = wv/3 (rows grp*16.. and +32768), seg = wv%3 covering
// ct in [cstart[seg], cstart[seg+1]). Partial (best,idx) -> pb_ws[row*3+seg].
#define TERM(sa, sb)                                                             \
  accL = __builtin_amdgcn_mfma_f32_16x16x32_bf16(aL[sa][0], B[(sb)*2+0], accL, 0, 0, 0); \
  accH = __builtin_amdgcn_mfma_f32_16x16x32_bf16(aH[sa][0], B[(sb)*2+0], accH, 0, 0, 0); \
  accL = __builtin_amdgcn_mfma_f32_16x16x32_bf16(aL[sa][1], B[(sb)*2+1], accL, 0, 0, 0); \
  accH = __builtin_amdgcn_mfma_f32_16x16x32_bf16(aH[sa][1], B[(sb)*2+1], accH, 0, 0, 0);

__global__ __launch_bounds__(256, 3) void vq_main2(
    const float* __restrict__ keys, const float* __restrict__ emb,
    const float* __restrict__ t_ws, const float* __restrict__ s_ws,
    const float* __restrict__ lse_ws, const unsigned short* __restrict__ wsb,
    float2* __restrict__ pb_ws, float* __restrict__ out) {
  const int tid = threadIdx.x;
  const int lane = tid & 63;
  const int wv = blockIdx.x * 4 + (tid >> 6);
  const int grp = wv / 3;
  const int seg = wv - grp * 3;
  const int ct0 = (seg == 0) ? 0 : (seg == 1 ? 86 : 171);
  const int ctN = (seg == 0) ? 86 : (seg == 1 ? 171 : 256);
  const int r16 = lane & 15;
  const int kg = lane >> 4;
  const int nlo = grp * 16, nhi = nlo + NPAIR;

  s16x8_t aL[3][2], aH[3][2];
  {
    const float* pL = keys + (size_t)(nlo + r16) * 64 + kg * 8;
    const float* pH = keys + (size_t)(nhi + r16) * 64 + kg * 8;
#pragma unroll
    for (int h = 0; h < 2; ++h) {
#pragma unroll
      for (int j = 0; j < 8; ++j) {
        float x = pL[h * 32 + j];
        unsigned short b0 = f2bf(x);
        float r1 = __fsub_rn(x, bf2f(b0));
        unsigned short b1 = f2bf(r1);
        float r2 = __fsub_rn(r1, bf2f(b1));
        aL[0][h][j] = (short)b0; aL[1][h][j] = (short)b1; aL[2][h][j] = (short)f2bf(r2);
        x = pH[h * 32 + j];
        b0 = f2bf(x); r1 = __fsub_rn(x, bf2f(b0)); b1 = f2bf(r1);
        r2 = __fsub_rn(r1, bf2f(b1));
        aH[0][h][j] = (short)b0; aH[1][h][j] = (short)b1; aH[2][h][j] = (short)f2bf(r2);
      }
    }
  }

  float sL[4], sH[4], lseL[4], lseH[4];
  uint32_t obL[4], obH[4];
#pragma unroll
  for (int r = 0; r < 4; ++r) {
    sL[r] = s_ws[nlo + kg * 4 + r];
    sH[r] = s_ws[nhi + kg * 4 + r];
    lseL[r] = lse_ws[nlo + kg * 4 + r];
    lseH[r] = lse_ws[nhi + kg * 4 + r];
    obL[r] = (uint32_t)(nlo + kg * 4 + r) * 4096u + (uint32_t)r16;
    obH[r] = (uint32_t)(nhi + kg * 4 + r) * 4096u + (uint32_t)r16;
  }

  float bestL[4], bestH[4];
  int biL[4], biH[4];
#pragma unroll
  for (int r = 0; r < 4; ++r) {
    bestL[r] = bestH[r] = -__builtin_inff();
    biL[r] = biH[r] = 0;
  }

  float* outLP = out + LP_OFF;
  const s16x8_t* bp = (const s16x8_t*)wsb + (size_t)ct0 * 6 * 64 + lane;

  s16x8_t B[6];
#pragma unroll
  for (int f = 0; f < 6; ++f) B[f] = bp[f * 64];

  for (int ct = ct0; ct < ctN; ++ct) {
    f32x4_t accL = {0.f, 0.f, 0.f, 0.f}, accH = {0.f, 0.f, 0.f, 0.f};
    TERM(1, 1) TERM(2, 0) TERM(0, 2) TERM(1, 0) TERM(0, 1) TERM(0, 0)

    const float tk = t_ws[ct * 16 + r16];
    if (ct < ctN - 1) {
      bp += 6 * 64;
#pragma unroll
      for (int f = 0; f < 6; ++f) B[f] = bp[f * 64];
    }

#pragma unroll
    for (int r = 0; r < 4; ++r) {
      const uint32_t j = obL[r] + (uint32_t)(ct * 16);
      uint32_t o0, o1;
      threefry(j, j + 0x08000000u, o0, o1);
      const float lL = __fsub_rn(__fsub_rn(__fmul_rn(2.0f, accL[r]), sL[r]), tk);
      const float lH = __fsub_rn(__fsub_rn(__fmul_rn(2.0f, accH[r]), sH[r]), tk);
      const float vL = __fadd_rn(lL, gumbel_bits(o0));
      const float vH = __fadd_rn(lH, gumbel_bits(o1));
      const int k = ct * 16 + r16;
      if (vL > bestL[r]) { bestL[r] = vL; biL[r] = k; }
      if (vH > bestH[r]) { bestH[r] = vH; biH[r] = k; }
      // non-temporal: write-once stream, keep it out of L2
      __builtin_nontemporal_store(__fsub_rn(lL, lseL[r]),
                                  &outLP[(size_t)obL[r] + (size_t)(ct * 16)]);
      __builtin_nontemporal_store(__fsub_rn(lH, lseH[r]),
                                  &outLP[(size_t)obH[r] + (size_t)(ct * 16)]);
    }
  }

  // reduce across the 16 lanes of each kg group (first-index tiebreak)
#pragma unroll
  for (int r = 0; r < 4; ++r) {
#pragma unroll
    for (int m = 1; m <= 8; m <<= 1) {
      float ov = __shfl_xor(bestL[r], m);
      int oi = __shfl_xor(biL[r], m);
      if (ov > bestL[r] || (ov == bestL[r] && oi < biL[r])) { bestL[r] = ov; biL[r] = oi; }
      ov = __shfl_xor(bestH[r], m);
      oi = __shfl_xor(biH[r], m);
      if (ov > bestH[r] || (ov == bestH[r] && oi < biH[r])) { bestH[r] = ov; biH[r] = oi; }
    }
  }

  // partial (best, idx) per row per ct-segment
  if (r16 == 0) {
#pragma unroll
    for (int r = 0; r < 4; ++r) {
      pb_ws[(size_t)(nlo + kg * 4 + r) * 3 + seg] =
          make_float2(bestL[r], __int_as_float(biL[r]));
      pb_ws[(size_t)(nhi + kg * 4 + r) * 3 + seg] =
          make_float2(bestH[r], __int_as_float(biH[r]));
    }
  }
}

// ---- K3: merge 3 ct-segments, gather winning code, write samples ----
__global__ __launch_bounds__(256) void vq_fin(const float* __restrict__ keys,
                                              const float* __restrict__ emb,
                                              const float2* __restrict__ pb_ws,
                                              float* __restrict__ out) {
  const int t = blockIdx.x * 256 + threadIdx.x;
  const int row = t >> 4, l16 = t & 15;
  const float2 a = pb_ws[(size_t)row * 3 + 0];
  const float2 b = pb_ws[(size_t)row * 3 + 1];
  const float2 c = pb_ws[(size_t)row * 3 + 2];
  float bv = a.x;
  int bi = __float_as_int(a.y);
  if (b.x > bv) { bv = b.x; bi = __float_as_int(b.y); }
  if (c.x > bv) { bv = c.x; bi = __float_as_int(c.y); }
  const float4 qq = *(const float4*)(emb + (size_t)bi * 64 + l16 * 4);
  const float4 kv = *(const float4*)(keys + (size_t)row * 64 + l16 * 4);
  float4 rr;
  rr.x = __fadd_rn(kv.x, __fsub_rn(qq.x, kv.x));
  rr.y = __fadd_rn(kv.y, __fsub_rn(qq.y, kv.y));
  rr.z = __fadd_rn(kv.z, __fsub_rn(qq.z, kv.z));
  rr.w = __fadd_rn(kv.w, __fsub_rn(qq.w, kv.w));
  *(float4*)(out + (size_t)row * 64 + l16 * 4) = rr;
}

extern "C" void kernel_launch(void* const* d_in, const int* in_sizes, int n_in,
                              void* d_out, int out_size, void* d_ws, size_t ws_size,
                              hipStream_t stream) {
  const float* keys = (const float*)d_in[0];
  const float* emb = (const float*)d_in[1];
  float* out = (float*)d_out;
  char* w = (char*)d_ws;
  float* t_ws = (float*)(w + WS_T);
  float* s_ws = (float*)(w + WS_S);
  float* lse_ws = (float*)(w + WS_LSE);
  unsigned short* e16 = (unsigned short*)(w + WS_E16);
  unsigned short* wsb = (unsigned short*)(w + WS_B);
  float2* pb_ws = (float2*)(w + WS_PB);
  float* pS_ws = (float*)(w + WS_PS);

  vq_pre<<<16, 256, 0, stream>>>(emb, t_ws, e16, wsb);
  vq_prek<<<256, 256, 0, stream>>>(keys, s_ws);
  vq_lsep<<<2048, 256, 0, stream>>>(keys, e16, t_ws, pS_ws);
  vq_lsefin<<<256, 256, 0, stream>>>(pS_ws, s_ws, lse_ws);
  vq_main2<<<1536, 256, 0, stream>>>(keys, emb, t_ws, s_ws, lse_ws, wsb, pb_ws, out);
  vq_fin<<<4096, 256, 0, stream>>>(keys, emb, pb_ws, out);
}